// Round 1
// baseline (857.167 us; speedup 1.0000x reference)
//
#include <hip/hip_runtime.h>
#include <hip/hip_bf16.h>

typedef unsigned short u16;
typedef unsigned int u32;
typedef __attribute__((ext_vector_type(4))) float f32x4;
typedef __attribute__((ext_vector_type(8))) short bf16x8;

#define DEVI static __device__ __forceinline__

DEVI u16 f2bf(float f) {
  u32 u = __builtin_bit_cast(u32, f);
  u += 0x7fffu + ((u >> 16) & 1u);
  return (u16)(u >> 16);
}

DEVI void gload_lds16(const void* g, void* l) {
  __builtin_amdgcn_global_load_lds(
      (const __attribute__((address_space(1))) u32*)g,
      (__attribute__((address_space(3))) u32*)l, 16, 0, 0);
}

// ---------------------------------------------------------------------------
// GEMM: C[M x BN] = A[M x K] @ B[K x BN], B given transposed: Bt[BN][K] (bf16)
// BM=64 rows/block, BK=64, 512 threads (8 waves, WM x WN wave grid).
// A is reg-staged (fp32 -> bf16 cvt or bf16 passthrough) with XOR-swizzled
// ds_write; B is staged via global_load_lds with inverse-swizzled global src.
// EPI: 0 = write bf16 transposed (outh[n][m]);
//      1 = x2 = bn2(relu(acc + b1)) -> outf fp32 (row stride BN)
//      2 = x1 = acc + b2 -> outf fp32 (row stride BN)
// ---------------------------------------------------------------------------
template<int BN, int WM, int WN, bool AF32, int EPI>
__global__ __launch_bounds__(512)
void gemm_bt(const void* __restrict__ Ap, const u16* __restrict__ Bt,
             const int K, const int M,
             float* __restrict__ outf, u16* __restrict__ outh,
             const float* __restrict__ e0, const float* __restrict__ e1,
             const float* __restrict__ e2, const float* __restrict__ e3,
             const float* __restrict__ e4)
{
  constexpr int BM = 64, BK = 64;
  static_assert(WM * WN == 8, "8 waves");
  constexpr int TM = BM / WM, TN = BN / WN;
  constexpr int MF = TM / 16, NF = TN / 16;
  constexpr int ABYTES = BM * BK * 2;      // 8 KiB
  constexpr int BBYTES = BN * BK * 2;      // BN*128 bytes

  __shared__ char smem[2 * ABYTES + 2 * BBYTES];

  const int tid = threadIdx.x;
  const int w = tid >> 6, l = tid & 63;
  const int wm = w / WN, wn = w % WN;
  const int l15 = l & 15, l4 = l >> 4;

  // XCD-aware swizzle (grid is a multiple of 8)
  const int nwg = gridDim.x;
  const int cpx = nwg >> 3;
  const int bid = blockIdx.x;
  const int wg = (bid & 7) * cpx + (bid >> 3);
  const int m0 = wg * BM;

  const int NT = K / BK;

  // A staging map: thread -> (row, 16B-chunk)
  const int ar = tid >> 3, ac = tid & 7;
  const int apos = (ar * 128 + ac * 16) ^ ((ar & 7) << 4);
  const size_t Abase = (size_t)(m0 + ar) * K + (size_t)ac * 8;

  f32x4 av0, av1;
  uint4 ah;

  f32x4 acc[MF][NF];
#pragma unroll
  for (int i = 0; i < MF; ++i)
#pragma unroll
    for (int j = 0; j < NF; ++j) acc[i][j] = (f32x4){0.f, 0.f, 0.f, 0.f};

  auto issueA = [&](int t) {
    if constexpr (AF32) {
      const float* p = (const float*)Ap + Abase + (size_t)t * BK;
      av0 = *(const f32x4*)p;
      av1 = *(const f32x4*)(p + 4);
    } else {
      const u16* p = (const u16*)Ap + Abase + (size_t)t * BK;
      ah = *(const uint4*)p;
    }
  };
  auto writeA = [&](int nb) {
    uint4 pk;
    if constexpr (AF32) {
      pk.x = (u32)f2bf(av0[0]) | ((u32)f2bf(av0[1]) << 16);
      pk.y = (u32)f2bf(av0[2]) | ((u32)f2bf(av0[3]) << 16);
      pk.z = (u32)f2bf(av1[0]) | ((u32)f2bf(av1[1]) << 16);
      pk.w = (u32)f2bf(av1[2]) | ((u32)f2bf(av1[3]) << 16);
    } else {
      pk = ah;
    }
    *(uint4*)(smem + nb * ABYTES + apos) = pk;
  };
  auto issueB = [&](int nb, int t) {
    const char* bsrc = (const char*)Bt + (size_t)t * (BK * 2);
    char* bdst = smem + 2 * ABYTES + nb * BBYTES + w * (BBYTES / 8);
#pragma unroll
    for (int j = 0; j < BN / 64; ++j) {
      const int p = w * (BBYTES / 8) + j * 1024 + l * 16;   // physical in tile
      const int q = p ^ (((p >> 7) & 7) << 4);              // logical (inv-swz)
      gload_lds16(bsrc + (size_t)(q >> 7) * ((size_t)K * 2) + (q & 127),
                  bdst + j * 1024);
    }
  };
  auto compute = [&](int cb) {
    const char* A = smem + cb * ABYTES;
    const char* B = smem + 2 * ABYTES + cb * BBYTES;
    bf16x8 af[MF][2], bfv[NF][2];
#pragma unroll
    for (int k2 = 0; k2 < 2; ++k2) {
#pragma unroll
      for (int mi = 0; mi < MF; ++mi) {
        const int row = wm * TM + mi * 16 + l15;
        const int off = (row * 128 + k2 * 64 + l4 * 16) ^ ((row & 7) << 4);
        af[mi][k2] = *(const bf16x8*)(A + off);
      }
#pragma unroll
      for (int ni = 0; ni < NF; ++ni) {
        const int n = wn * TN + ni * 16 + l15;
        const int off = (n * 128 + k2 * 64 + l4 * 16) ^ ((n & 7) << 4);
        bfv[ni][k2] = *(const bf16x8*)(B + off);
      }
    }
#pragma unroll
    for (int k2 = 0; k2 < 2; ++k2)
#pragma unroll
      for (int mi = 0; mi < MF; ++mi)
#pragma unroll
        for (int ni = 0; ni < NF; ++ni)
          acc[mi][ni] = __builtin_amdgcn_mfma_f32_16x16x32_bf16(
              af[mi][k2], bfv[ni][k2], acc[mi][ni], 0, 0, 0);
  };

  // prologue
  issueB(0, 0);
  issueA(0);
  writeA(0);
  __syncthreads();

  for (int t = 0; t < NT; ++t) {
    const int cur = t & 1, nxt = cur ^ 1;
    const bool more = (t + 1 < NT);
    if (more) { issueB(nxt, t + 1); issueA(t + 1); }
    compute(cur);
    if (more) writeA(nxt);
    __syncthreads();
  }

  // epilogue
  const int mrow0 = m0 + wm * TM + l4 * 4;
#pragma unroll
  for (int ni = 0; ni < NF; ++ni) {
    const int n = wn * TN + ni * 16 + l15;
    if constexpr (EPI == 0) {
#pragma unroll
      for (int mi = 0; mi < MF; ++mi) {
        const int m = mrow0 + mi * 16;
        ushort4 o;
        o.x = f2bf(acc[mi][ni][0]);
        o.y = f2bf(acc[mi][ni][1]);
        o.z = f2bf(acc[mi][ni][2]);
        o.w = f2bf(acc[mi][ni][3]);
        *(ushort4*)(outh + (size_t)n * M + m) = o;
      }
    } else if constexpr (EPI == 1) {
      const float b1v = e0[n];
      const float sc = e1[n] * rsqrtf(e4[n] + 1e-5f);
      const float sh = e2[n] - e3[n] * sc;
#pragma unroll
      for (int mi = 0; mi < MF; ++mi)
#pragma unroll
        for (int r = 0; r < 4; ++r) {
          const int m = mrow0 + mi * 16 + r;
          float s = acc[mi][ni][r] + b1v;
          s = fmaxf(s, 0.f);
          outf[(size_t)m * BN + n] = s * sc + sh;
        }
    } else {
      const float b2v = e0[n];
#pragma unroll
      for (int mi = 0; mi < MF; ++mi)
#pragma unroll
        for (int r = 0; r < 4; ++r) {
          const int m = mrow0 + mi * 16 + r;
          outf[(size_t)m * BN + n] = acc[mi][ni][r] + b2v;
        }
    }
  }
}

// ---------------------------------------------------------------------------
// bn1(x) -> bf16, vectorized 8 elems/thread (row length 512 divides 8)
// ---------------------------------------------------------------------------
__global__ __launch_bounds__(256)
void bn1_cast_k(const float* __restrict__ x, const float* __restrict__ g,
                const float* __restrict__ be, const float* __restrict__ rm,
                const float* __restrict__ rv, u16* __restrict__ out)
{
  const size_t i8 = ((size_t)blockIdx.x * 256 + threadIdx.x) * 8;
  const f32x4 v0 = *(const f32x4*)(x + i8);
  const f32x4 v1 = *(const f32x4*)(x + i8 + 4);
  const int f0 = (int)(i8 & 511);
  u16 u[8];
#pragma unroll
  for (int e = 0; e < 8; ++e) {
    const int f = f0 + e;
    const float sc = g[f] * rsqrtf(rv[f] + 1e-5f);
    const float v = (e < 4) ? v0[e] : v1[e - 4];
    u[e] = f2bf((v - rm[f]) * sc + be[f]);
  }
  uint4 o;
  o.x = (u32)u[0] | ((u32)u[1] << 16);
  o.y = (u32)u[2] | ((u32)u[3] << 16);
  o.z = (u32)u[4] | ((u32)u[5] << 16);
  o.w = (u32)u[6] | ((u32)u[7] << 16);
  *(uint4*)(out + i8) = o;
}

// out[n][k] = bf16(in[k][n]); out has 512 columns (k), in row length = rowlen
__global__ __launch_bounds__(256)
void tcvt_k(const float* __restrict__ in, u16* __restrict__ out, int rowlen)
{
  const int o = blockIdx.x * 256 + threadIdx.x;
  const int n = o >> 9, k = o & 511;
  out[o] = f2bf(in[(size_t)k * rowlen + n]);
}

// ---------------------------------------------------------------------------
extern "C" void kernel_launch(void* const* d_in, const int* in_sizes, int n_in,
                              void* d_out, int out_size, void* d_ws, size_t ws_size,
                              hipStream_t stream)
{
  const float* x   = (const float*)d_in[0];
  const float* a   = (const float*)d_in[1];
  const float* w1  = (const float*)d_in[2];
  const float* b1  = (const float*)d_in[3];
  const float* w2  = (const float*)d_in[4];
  const float* b2  = (const float*)d_in[5];
  const float* g1  = (const float*)d_in[6];
  const float* be1 = (const float*)d_in[7];
  const float* rm1 = (const float*)d_in[8];
  const float* rv1 = (const float*)d_in[9];
  const float* g2  = (const float*)d_in[10];
  const float* be2 = (const float*)d_in[11];
  const float* rm2 = (const float*)d_in[12];
  const float* rv2 = (const float*)d_in[13];

  constexpr int N = 16384, F = 512, H = 512, C = 128;
  float* out_x1 = (float*)d_out;                    // [N][C]
  float* out_x2 = (float*)d_out + (size_t)N * C;    // [N][H]

  char* wsp = (char*)d_ws;
  u16* xb  = (u16*)wsp;  wsp += (size_t)N * F * 2;  // bn1(x) bf16      16 MiB
  u16* t_t = (u16*)wsp;  wsp += (size_t)H * N * 2;  // (bn1x@w1)^T      16 MiB
  u16* z_t = (u16*)wsp;  wsp += (size_t)C * N * 2;  // (x2@w2)^T         4 MiB
  u16* w1t = (u16*)wsp;  wsp += (size_t)H * F * 2;  // w1^T bf16
  u16* w2t = (u16*)wsp;  wsp += (size_t)C * H * 2;  // w2^T bf16

  // k0: elementwise prep
  bn1_cast_k<<<(N * F / 8) / 256, 256, 0, stream>>>(x, g1, be1, rm1, rv1, xb);
  tcvt_k<<<(F * H) / 256, 256, 0, stream>>>(w1, w1t, H);   // w1t[h][f]
  tcvt_k<<<(H * C) / 256, 256, 0, stream>>>(w2, w2t, C);   // w2t[c][h]

  // k1: t = bn1x @ w1  -> t_t[h][node] bf16
  gemm_bt<512, 1, 8, false, 0><<<N / 64, 512, 0, stream>>>(
      xb, w1t, F, N, nullptr, t_t, nullptr, nullptr, nullptr, nullptr, nullptr);

  // k2: x2 = bn2(relu(a @ t + b1)) -> out_x2 fp32
  gemm_bt<512, 1, 8, true, 1><<<N / 64, 512, 0, stream>>>(
      a, t_t, N, N, out_x2, nullptr, b1, g2, be2, rm2, rv2);

  // k3: z = x2 @ w2 -> z_t[c][node] bf16  (A = x2 fp32 from d_out)
  gemm_bt<128, 2, 4, true, 0><<<N / 64, 512, 0, stream>>>(
      out_x2, w2t, H, N, nullptr, z_t, nullptr, nullptr, nullptr, nullptr, nullptr);

  // k4: x1 = a @ z + b2 -> out_x1 fp32
  gemm_bt<128, 2, 4, true, 2><<<N / 64, 512, 0, stream>>>(
      a, z_t, N, N, out_x1, nullptr, b2, nullptr, nullptr, nullptr, nullptr);
}